// Round 1
// 838.821 us; speedup vs baseline: 1.0437x; 1.0437x over previous
//
#include <hip/hip_runtime.h>
#include <hip/hip_bf16.h>
#include <stdint.h>

#define B_ 32
#define S_ 4096
#define D_ 1024
#define H_ 512
#define BK 32
#define NCHUNK 64   // S_/64 score chunks per batch

typedef __bf16 bf16_t;
typedef bf16_t bf16x8 __attribute__((ext_vector_type(8)));
typedef float f32x4 __attribute__((ext_vector_type(4)));

#define AS_STRIDE 40  // 32 k + pad: 80 B rows, 2-way-only bank aliasing on b128

// ---------------------------------------------------------------------------
// Kernel 0 (prep): W1bf[kb][h][kk] = bf16( W1[kb*32+kk][h] )  (unchanged)
// ---------------------------------------------------------------------------
__global__ __launch_bounds__(256)
void ta_prep_kernel(const float* __restrict__ W1, bf16_t* __restrict__ W1bf)
{
    const int kb = blockIdx.x;   // 0..31
    const int t  = threadIdx.x;

#pragma unroll
    for (int hh = 0; hh < 2; ++hh) {
        int h = t + hh * 256;
        bf16_t row[BK];
#pragma unroll
        for (int kk = 0; kk < BK; ++kk)
            row[kk] = (bf16_t)W1[(size_t)(kb * BK + kk) * H_ + h];
        bf16_t* dst = W1bf + ((size_t)kb * H_ + h) * BK;
#pragma unroll
        for (int c = 0; c < 4; ++c)
            *(bf16x8*)(dst + c * 8) = *(const bf16x8*)&row[c * 8];
    }
}

// ---------------------------------------------------------------------------
// Kernel 1 (FUSED): scores for 64 rows (same MFMA GEMM as before), then
// block-local flash softmax (m, l, unnormalized w) and the 64-row weighted
// partial sum  pout[b][chunk][d] = sum_s exp(score_s - m) * x[b,s,d].
// The x rows were just streamed for the GEMM -> re-read hits L2/L3, so x
// crosses HBM exactly ONCE for the whole problem.
// ---------------------------------------------------------------------------
__global__ __launch_bounds__(256, 2)
void ta_fused_kernel(const float* __restrict__ x,      // [B,S,D]
                     const float* __restrict__ prev,   // [B,D]
                     const bf16_t* __restrict__ W1bf,  // [32][512][32]
                     const float* __restrict__ b1,
                     const float* __restrict__ w2,
                     const float* __restrict__ b2,
                     float* __restrict__ pout,         // [B][NCHUNK][D]
                     float* __restrict__ mlbuf)        // [B][NCHUNK][2]
{
    __shared__ bf16_t As[64 * AS_STRIDE];    // 5120 B
    __shared__ bf16_t Bs[H_ * BK];           // 32768 B, [h][kk], no pad (DMA dest)
    __shared__ float  scoreS[4][64];
    __shared__ float  wS[64];

    const int t    = threadIdx.x;
    const int wv   = t >> 6;
    const int lane = t & 63;
    const int quad = lane >> 4;
    const int n16  = lane & 15;

    const int b  = blockIdx.y;
    const int s0 = blockIdx.x * 64;

    const int ar = t >> 2;
    const int ac = (t & 3) * 8;
    const float* xrow  = x + ((size_t)b * S_ + s0 + ar) * D_;
    const float* prevb = prev + (size_t)b * D_;

    float b1v[8], w2v[8];
#pragma unroll
    for (int j = 0; j < 8; ++j) {
        int h = wv * 128 + j * 16 + n16;
        b1v[j] = b1[h];
        w2v[j] = w2[h];
    }

    f32x4 acc[4][8];
#pragma unroll
    for (int i = 0; i < 4; ++i)
#pragma unroll
        for (int j = 0; j < 8; ++j)
            acc[i][j] = (f32x4){0.f, 0.f, 0.f, 0.f};

    for (int kb = 0; kb < D_ / BK; ++kb) {
        // global loads issued before the barrier (overlap prior MFMA)
        f32x4 a0 = *(const f32x4*)(xrow + kb * BK + ac);
        f32x4 a1 = *(const f32x4*)(xrow + kb * BK + ac + 4);
        f32x4 p0 = *(const f32x4*)(prevb + kb * BK + ac);      // L1-resident
        f32x4 p1 = *(const f32x4*)(prevb + kb * BK + ac + 4);

        __syncthreads();  // prior iteration's frag reads complete

        // ---- B tile: 32 KiB contiguous DMA, wave wv does 8x1KiB ----
        const char* gB = (const char*)(W1bf + (size_t)kb * H_ * BK);
#pragma unroll
        for (int r = 0; r < 8; ++r) {
            int off = (wv * 8 + r) * 1024;
            __builtin_amdgcn_global_load_lds(
                (const __attribute__((address_space(1))) void*)(gB + off + lane * 16),
                (__attribute__((address_space(3))) void*)((char*)Bs + off),
                16, 0, 0);
        }

        // ---- A tile: scale by prev, convert, vector LDS write ----
        {
            a0 *= p0;
            a1 *= p1;
            bf16x8 aw;
#pragma unroll
            for (int e = 0; e < 4; ++e) { aw[e] = (bf16_t)a0[e]; aw[4 + e] = (bf16_t)a1[e]; }
            *(bf16x8*)&As[ar * AS_STRIDE + ac] = aw;
        }

        __syncthreads();  // staging (incl. DMA vmcnt drain) visible

        bf16x8 afr[4];
#pragma unroll
        for (int i = 0; i < 4; ++i)
            afr[i] = *(const bf16x8*)&As[(i * 16 + n16) * AS_STRIDE + quad * 8];
#pragma unroll
        for (int j = 0; j < 8; ++j) {
            bf16x8 bfr = *(const bf16x8*)&Bs[(wv * 128 + j * 16 + n16) * BK + quad * 8];
#pragma unroll
            for (int i = 0; i < 4; ++i)
                acc[i][j] = __builtin_amdgcn_mfma_f32_16x16x32_bf16(afr[i], bfr, acc[i][j], 0, 0, 0);
        }
    }

    // ---- epilogue: bias + relu + dot(w2), reduce over h ----
    // acc[i][j][r] = hidden[row = i*16 + quad*4 + r][h = wv*128 + j*16 + n16]
    float part[4][4];
#pragma unroll
    for (int i = 0; i < 4; ++i)
#pragma unroll
        for (int r = 0; r < 4; ++r) {
            float p = 0.f;
#pragma unroll
            for (int j = 0; j < 8; ++j) {
                float hval = acc[i][j][r] + b1v[j];
                hval = fmaxf(hval, 0.f);
                p += hval * w2v[j];
            }
            for (int off = 8; off > 0; off >>= 1)
                p += __shfl_xor(p, off);
            part[i][r] = p;
        }

    if (n16 == 0) {
#pragma unroll
        for (int i = 0; i < 4; ++i)
#pragma unroll
            for (int r = 0; r < 4; ++r)
                scoreS[wv][i * 16 + quad * 4 + r] = part[i][r];
    }
    __syncthreads();

    // ---- block-local flash softmax over the 64 scores (wave 0 only) ----
    if (t < 64) {
        float sc = scoreS[0][t] + scoreS[1][t] + scoreS[2][t] + scoreS[3][t] + b2[0];
        float m = sc;
#pragma unroll
        for (int off = 32; off > 0; off >>= 1)
            m = fmaxf(m, __shfl_xor(m, off));
        float wexp = __expf(sc - m);
        float l = wexp;
#pragma unroll
        for (int off = 32; off > 0; off >>= 1)
            l += __shfl_xor(l, off);
        wS[t] = wexp;
        if (t == 0) {
            float* ml = mlbuf + ((size_t)b * NCHUNK + blockIdx.x) * 2;
            ml[0] = m;
            ml[1] = l;
        }
    }
    __syncthreads();

    // ---- 64-row weighted partial sum (rows are L2/L3-hot from the GEMM) ----
    // thread t owns columns [t*4, t*4+4)
    const float* xb = x + ((size_t)b * S_ + s0) * D_;
    f32x4 acc0 = (f32x4){0.f,0.f,0.f,0.f}, acc1 = acc0, acc2 = acc0, acc3 = acc0;
    for (int s = 0; s < 64; s += 4) {
        f32x4 x0 = *(const f32x4*)(xb + (size_t)(s + 0) * D_ + t * 4);
        f32x4 x1 = *(const f32x4*)(xb + (size_t)(s + 1) * D_ + t * 4);
        f32x4 x2 = *(const f32x4*)(xb + (size_t)(s + 2) * D_ + t * 4);
        f32x4 x3 = *(const f32x4*)(xb + (size_t)(s + 3) * D_ + t * 4);
        acc0 += x0 * wS[s + 0];
        acc1 += x1 * wS[s + 1];
        acc2 += x2 * wS[s + 2];
        acc3 += x3 * wS[s + 3];
    }
    f32x4 r = (acc0 + acc1) + (acc2 + acc3);
    *(f32x4*)(pout + ((size_t)b * NCHUNK + blockIdx.x) * D_ + t * 4) = r;
}

// ---------------------------------------------------------------------------
// Kernel 2 (combine): out[b,d] = sum_c exp(m_c - M)/L * pout[b][c][d]
// with M = max_c m_c, L = sum_c l_c * exp(m_c - M).  8 MiB read total.
// grid (D/256, B); thread t owns one column d = blockIdx.x*256 + t.
// ---------------------------------------------------------------------------
__global__ __launch_bounds__(256)
void ta_combine_kernel(const float* __restrict__ pout,   // [B][NCHUNK][D]
                       const float* __restrict__ mlbuf,  // [B][NCHUNK][2]
                       float* __restrict__ out)          // [B,D]
{
    const int b = blockIdx.y;
    const int t = threadIdx.x;
    const int d = blockIdx.x * 256 + t;

    __shared__ float scaleS[NCHUNK];
    if (t < NCHUNK) {
        const float* ml = mlbuf + ((size_t)b * NCHUNK + t) * 2;
        float m = ml[0];
        float l = ml[1];
        float M = m;
#pragma unroll
        for (int off = 32; off > 0; off >>= 1)
            M = fmaxf(M, __shfl_xor(M, off));
        float le = l * __expf(m - M);
        float L = le;
#pragma unroll
        for (int off = 32; off > 0; off >>= 1)
            L += __shfl_xor(L, off);
        scaleS[t] = __expf(m - M) / L;
    }
    __syncthreads();

    const float* pb = pout + (size_t)b * NCHUNK * D_ + d;
    float a0 = 0.f, a1 = 0.f, a2 = 0.f, a3 = 0.f;
#pragma unroll 4
    for (int c = 0; c < NCHUNK; c += 4) {
        a0 += pb[(size_t)(c + 0) * D_] * scaleS[c + 0];
        a1 += pb[(size_t)(c + 1) * D_] * scaleS[c + 1];
        a2 += pb[(size_t)(c + 2) * D_] * scaleS[c + 2];
        a3 += pb[(size_t)(c + 3) * D_] * scaleS[c + 3];
    }
    out[(size_t)b * D_ + d] = (a0 + a1) + (a2 + a3);
}

// ---------------------------------------------------------------------------
extern "C" void kernel_launch(void* const* d_in, const int* in_sizes, int n_in,
                              void* d_out, int out_size, void* d_ws, size_t ws_size,
                              hipStream_t stream) {
    const float* x    = (const float*)d_in[0];
    const float* prev = (const float*)d_in[1];
    const float* W1   = (const float*)d_in[2];
    const float* b1   = (const float*)d_in[3];
    const float* w2   = (const float*)d_in[4];
    const float* b2   = (const float*)d_in[5];
    float* out = (float*)d_out;

    // workspace layout — 9.02 MiB total
    bf16_t* W1bf  = (bf16_t*)d_ws;                                   // 1 MiB
    float*  pout  = (float*)((char*)d_ws + (size_t)1 * 1024 * 1024); // 8 MiB
    float*  mlbuf = (float*)((char*)d_ws + (size_t)9 * 1024 * 1024); // 16 KiB

    ta_prep_kernel<<<32, 256, 0, stream>>>(W1, W1bf);

    dim3 g1(NCHUNK, B_);   // 2048 workgroups
    ta_fused_kernel<<<g1, 256, 0, stream>>>(x, prev, W1bf, b1, w2, b2, pout, mlbuf);

    dim3 g2(D_ / 256, B_); // 128 workgroups
    ta_combine_kernel<<<g2, 256, 0, stream>>>(pout, mlbuf, out);
}

// Round 2
// 830.632 us; speedup vs baseline: 1.0540x; 1.0099x over previous
//
#include <hip/hip_runtime.h>
#include <hip/hip_bf16.h>
#include <stdint.h>

#define B_ 32
#define S_ 4096
#define D_ 1024
#define H_ 512
#define BK 32
#define NCHUNK 64   // S_/64 score chunks per batch

typedef __bf16 bf16_t;
typedef bf16_t bf16x8 __attribute__((ext_vector_type(8)));
typedef float f32x4 __attribute__((ext_vector_type(4)));

#define AS_STRIDE 40  // 32 k + pad: 80 B rows, 2-way-only bank aliasing on b128

// ---------------------------------------------------------------------------
// Kernel 0 (prep): W1bf[kb][h][kk] = bf16( W1[kb*32+kk][h] )  (unchanged)
// ---------------------------------------------------------------------------
__global__ __launch_bounds__(256)
void ta_prep_kernel(const float* __restrict__ W1, bf16_t* __restrict__ W1bf)
{
    const int kb = blockIdx.x;   // 0..31
    const int t  = threadIdx.x;

#pragma unroll
    for (int hh = 0; hh < 2; ++hh) {
        int h = t + hh * 256;
        bf16_t row[BK];
#pragma unroll
        for (int kk = 0; kk < BK; ++kk)
            row[kk] = (bf16_t)W1[(size_t)(kb * BK + kk) * H_ + h];
        bf16_t* dst = W1bf + ((size_t)kb * H_ + h) * BK;
#pragma unroll
        for (int c = 0; c < 4; ++c)
            *(bf16x8*)(dst + c * 8) = *(const bf16x8*)&row[c * 8];
    }
}

// ---------------------------------------------------------------------------
// Kernel 1 (FUSED, 2-phase pipelined): scores GEMM with double-buffered
// As/Bs, counted vmcnt(2) + raw s_barrier (T3/T4 minimum recipe), then
// block-local flash softmax and the 64-row weighted partial sum.
//
// Per-iteration VMEM per wave is EXACTLY [8 global_load_lds][2 x-loads]
// (prefetch indices clamped so the count is invariant) -> vmcnt(2) leaves
// only the 2 x-prefetch loads in flight across the barrier.
// ---------------------------------------------------------------------------
__global__ __launch_bounds__(256, 2)
void ta_fused_kernel(const float* __restrict__ x,      // [B,S,D]
                     const float* __restrict__ prev,   // [B,D]
                     const bf16_t* __restrict__ W1bf,  // [32][512][32]
                     const float* __restrict__ b1,
                     const float* __restrict__ w2,
                     const float* __restrict__ b2,
                     float* __restrict__ pout,         // [B][NCHUNK][D]
                     float* __restrict__ mlbuf)        // [B][NCHUNK][2]
{
    __shared__ bf16_t As[2][64 * AS_STRIDE];   // 2 x 5120 B
    __shared__ bf16_t Bs[2][H_ * BK];          // 2 x 32768 B (DMA dest, no pad)
    __shared__ float  prevS[D_];               // 4096 B
    __shared__ float  scoreS[4][64];           // 1024 B
    __shared__ float  wS[64];                  // 256 B   -> total 81152 B < 80 KiB

    const int t    = threadIdx.x;
    const int wv   = t >> 6;
    const int lane = t & 63;
    const int quad = lane >> 4;
    const int n16  = lane & 15;

    const int b  = blockIdx.y;
    const int s0 = blockIdx.x * 64;

    const int ar = t >> 2;
    const int ac = (t & 3) * 8;
    const float* xrow  = x + ((size_t)b * S_ + s0 + ar) * D_;
    const float* prevb = prev + (size_t)b * D_;

    f32x4 acc[4][8];
#pragma unroll
    for (int i = 0; i < 4; ++i)
#pragma unroll
        for (int j = 0; j < 8; ++j)
            acc[i][j] = (f32x4){0.f, 0.f, 0.f, 0.f};

    // ---- prologue: prevS, x(0) regs, DMA B(0) -> Bs[0] ----
    *(f32x4*)&prevS[t * 4] = *(const f32x4*)(prevb + t * 4);

    f32x4 xA0 = *(const f32x4*)(xrow + ac);
    f32x4 xA1 = *(const f32x4*)(xrow + ac + 4);

    {
        const char* gB = (const char*)W1bf;   // kb = 0 chunk
#pragma unroll
        for (int r = 0; r < 8; ++r) {
            int off = (wv * 8 + r) * 1024;
            __builtin_amdgcn_global_load_lds(
                (const __attribute__((address_space(1))) void*)(gB + off + lane * 16),
                (__attribute__((address_space(3))) void*)((char*)Bs[0] + off),
                16, 0, 0);
        }
    }
    __syncthreads();   // full drain once: prevS, Bs[0], xA all ready

    // As[0] write from x(0)
    {
        f32x4 pv0 = *(const f32x4*)&prevS[ac];
        f32x4 pv1 = *(const f32x4*)&prevS[ac + 4];
        f32x4 sc0 = xA0 * pv0, sc1 = xA1 * pv1;
        bf16x8 aw;
#pragma unroll
        for (int e = 0; e < 4; ++e) { aw[e] = (bf16_t)sc0[e]; aw[4 + e] = (bf16_t)sc1[e]; }
        *(bf16x8*)&As[0][ar * AS_STRIDE + ac] = aw;
    }
    // issue x(1) -> xB (stays in flight across the barrier)
    f32x4 xB0 = *(const f32x4*)(xrow + BK + ac);
    f32x4 xB1 = *(const f32x4*)(xrow + BK + ac + 4);

    asm volatile("s_waitcnt lgkmcnt(0)\n\ts_barrier" ::: "memory");
    // invariant at loop entry: As[0],Bs[0] valid; exactly 2 VMEM (xB) in flight

#define TA_BODY(KB, CBUF, XU0, XU1, XN0, XN1)                                    \
    {                                                                            \
        const int kb_ = (KB);                                                    \
        bf16x8 afr[4];                                                           \
        _Pragma("unroll")                                                        \
        for (int i = 0; i < 4; ++i)                                              \
            afr[i] = *(const bf16x8*)&As[CBUF][(i * 16 + n16) * AS_STRIDE + quad * 8]; \
        /* write next A tile from regs loaded last body (clamped index) */       \
        {                                                                        \
            const int kp = (kb_ + 1 < 32) ? kb_ + 1 : 31;                        \
            f32x4 pv0 = *(const f32x4*)&prevS[kp * BK + ac];                     \
            f32x4 pv1 = *(const f32x4*)&prevS[kp * BK + ac + 4];                 \
            f32x4 sc0 = XU0 * pv0, sc1 = XU1 * pv1;                              \
            bf16x8 aw;                                                           \
            _Pragma("unroll")                                                    \
            for (int e = 0; e < 4; ++e) { aw[e] = (bf16_t)sc0[e]; aw[4 + e] = (bf16_t)sc1[e]; } \
            *(bf16x8*)&As[(CBUF) ^ 1][ar * AS_STRIDE + ac] = aw;                 \
        }                                                                        \
        /* DMA next B tile into the free buffer (clamped index) */               \
        {                                                                        \
            const int kp = (kb_ + 1 < 32) ? kb_ + 1 : 31;                        \
            const char* gB = (const char*)(W1bf + (size_t)kp * H_ * BK);         \
            char* lB = (char*)Bs[(CBUF) ^ 1];                                    \
            _Pragma("unroll")                                                    \
            for (int r = 0; r < 8; ++r) {                                        \
                int off = (wv * 8 + r) * 1024;                                   \
                __builtin_amdgcn_global_load_lds(                                \
                    (const __attribute__((address_space(1))) void*)(gB + off + lane * 16), \
                    (__attribute__((address_space(3))) void*)(lB + off), 16, 0, 0); \
            }                                                                    \
        }                                                                        \
        /* prefetch x(kb+2) (clamped so 2 loads are ALWAYS issued) */            \
        {                                                                        \
            const int kp2 = (kb_ + 2 < 32) ? kb_ + 2 : 31;                       \
            XN0 = *(const f32x4*)(xrow + kp2 * BK + ac);                         \
            XN1 = *(const f32x4*)(xrow + kp2 * BK + ac + 4);                     \
        }                                                                        \
        /* MFMA on current buffers (compiler interleaves bfr ds_reads) */        \
        _Pragma("unroll")                                                        \
        for (int j = 0; j < 8; ++j) {                                            \
            bf16x8 bfr = *(const bf16x8*)&Bs[CBUF][(wv * 128 + j * 16 + n16) * BK + quad * 8]; \
            _Pragma("unroll")                                                    \
            for (int i = 0; i < 4; ++i)                                          \
                acc[i][j] = __builtin_amdgcn_mfma_f32_16x16x32_bf16(afr[i], bfr, acc[i][j], 0, 0, 0); \
        }                                                                        \
        /* counted drain: 8 DMAs done, 2 x-prefetch stay in flight */            \
        asm volatile("s_waitcnt vmcnt(2) lgkmcnt(0)\n\ts_barrier" ::: "memory"); \
    }

    for (int kb2 = 0; kb2 < 32; kb2 += 2) {
        TA_BODY(kb2,     0, xB0, xB1, xA0, xA1);   // even step: uses x(kb+1)=xB
        TA_BODY(kb2 + 1, 1, xA0, xA1, xB0, xB1);   // odd  step: uses x(kb+1)=xA
    }
#undef TA_BODY

    // ---- epilogue: bias + relu + dot(w2), reduce over h ----
    // acc[i][j][r] = hidden[row = i*16 + quad*4 + r][h = wv*128 + j*16 + n16]
    float b1v[8], w2v[8];
#pragma unroll
    for (int j = 0; j < 8; ++j) {
        int h = wv * 128 + j * 16 + n16;
        b1v[j] = b1[h];
        w2v[j] = w2[h];
    }

    float part[4][4];
#pragma unroll
    for (int i = 0; i < 4; ++i)
#pragma unroll
        for (int r = 0; r < 4; ++r) {
            float p = 0.f;
#pragma unroll
            for (int j = 0; j < 8; ++j) {
                float hval = acc[i][j][r] + b1v[j];
                hval = fmaxf(hval, 0.f);
                p += hval * w2v[j];
            }
            for (int off = 8; off > 0; off >>= 1)
                p += __shfl_xor(p, off);
            part[i][r] = p;
        }

    if (n16 == 0) {
#pragma unroll
        for (int i = 0; i < 4; ++i)
#pragma unroll
            for (int r = 0; r < 4; ++r)
                scoreS[wv][i * 16 + quad * 4 + r] = part[i][r];
    }
    __syncthreads();

    // ---- block-local flash softmax over the 64 scores (wave 0 only) ----
    if (t < 64) {
        float sc = scoreS[0][t] + scoreS[1][t] + scoreS[2][t] + scoreS[3][t] + b2[0];
        float m = sc;
#pragma unroll
        for (int off = 32; off > 0; off >>= 1)
            m = fmaxf(m, __shfl_xor(m, off));
        float wexp = __expf(sc - m);
        float l = wexp;
#pragma unroll
        for (int off = 32; off > 0; off >>= 1)
            l += __shfl_xor(l, off);
        wS[t] = wexp;
        if (t == 0) {
            float* ml = mlbuf + ((size_t)b * NCHUNK + blockIdx.x) * 2;
            ml[0] = m;
            ml[1] = l;
        }
    }
    __syncthreads();

    // ---- 64-row weighted partial sum (rows are L2/L3-hot from the GEMM) ----
    const float* xb = x + ((size_t)b * S_ + s0) * D_;
    f32x4 acc0 = (f32x4){0.f,0.f,0.f,0.f}, acc1 = acc0, acc2 = acc0, acc3 = acc0;
    for (int s = 0; s < 64; s += 4) {
        f32x4 x0 = *(const f32x4*)(xb + (size_t)(s + 0) * D_ + t * 4);
        f32x4 x1 = *(const f32x4*)(xb + (size_t)(s + 1) * D_ + t * 4);
        f32x4 x2 = *(const f32x4*)(xb + (size_t)(s + 2) * D_ + t * 4);
        f32x4 x3 = *(const f32x4*)(xb + (size_t)(s + 3) * D_ + t * 4);
        acc0 += x0 * wS[s + 0];
        acc1 += x1 * wS[s + 1];
        acc2 += x2 * wS[s + 2];
        acc3 += x3 * wS[s + 3];
    }
    f32x4 r = (acc0 + acc1) + (acc2 + acc3);
    *(f32x4*)(pout + ((size_t)b * NCHUNK + blockIdx.x) * D_ + t * 4) = r;
}

// ---------------------------------------------------------------------------
// Kernel 2 (combine): out[b,d] = sum_c exp(m_c - M)/L * pout[b][c][d]
// ---------------------------------------------------------------------------
__global__ __launch_bounds__(256)
void ta_combine_kernel(const float* __restrict__ pout,   // [B][NCHUNK][D]
                       const float* __restrict__ mlbuf,  // [B][NCHUNK][2]
                       float* __restrict__ out)          // [B,D]
{
    const int b = blockIdx.y;
    const int t = threadIdx.x;
    const int d = blockIdx.x * 256 + t;

    __shared__ float scaleS[NCHUNK];
    if (t < NCHUNK) {
        const float* ml = mlbuf + ((size_t)b * NCHUNK + t) * 2;
        float m = ml[0];
        float l = ml[1];
        float M = m;
#pragma unroll
        for (int off = 32; off > 0; off >>= 1)
            M = fmaxf(M, __shfl_xor(M, off));
        float le = l * __expf(m - M);
        float L = le;
#pragma unroll
        for (int off = 32; off > 0; off >>= 1)
            L += __shfl_xor(L, off);
        scaleS[t] = __expf(m - M) / L;
    }
    __syncthreads();

    const float* pb = pout + (size_t)b * NCHUNK * D_ + d;
    float a0 = 0.f, a1 = 0.f, a2 = 0.f, a3 = 0.f;
#pragma unroll 4
    for (int c = 0; c < NCHUNK; c += 4) {
        a0 += pb[(size_t)(c + 0) * D_] * scaleS[c + 0];
        a1 += pb[(size_t)(c + 1) * D_] * scaleS[c + 1];
        a2 += pb[(size_t)(c + 2) * D_] * scaleS[c + 2];
        a3 += pb[(size_t)(c + 3) * D_] * scaleS[c + 3];
    }
    out[(size_t)b * D_ + d] = (a0 + a1) + (a2 + a3);
}

// ---------------------------------------------------------------------------
extern "C" void kernel_launch(void* const* d_in, const int* in_sizes, int n_in,
                              void* d_out, int out_size, void* d_ws, size_t ws_size,
                              hipStream_t stream) {
    const float* x    = (const float*)d_in[0];
    const float* prev = (const float*)d_in[1];
    const float* W1   = (const float*)d_in[2];
    const float* b1   = (const float*)d_in[3];
    const float* w2   = (const float*)d_in[4];
    const float* b2   = (const float*)d_in[5];
    float* out = (float*)d_out;

    // workspace layout — 9.02 MiB total
    bf16_t* W1bf  = (bf16_t*)d_ws;                                   // 1 MiB
    float*  pout  = (float*)((char*)d_ws + (size_t)1 * 1024 * 1024); // 8 MiB
    float*  mlbuf = (float*)((char*)d_ws + (size_t)9 * 1024 * 1024); // 16 KiB

    ta_prep_kernel<<<32, 256, 0, stream>>>(W1, W1bf);

    dim3 g1(NCHUNK, B_);   // 2048 workgroups
    ta_fused_kernel<<<g1, 256, 0, stream>>>(x, prev, W1bf, b1, w2, b2, pout, mlbuf);

    dim3 g2(D_ / 256, B_); // 128 workgroups
    ta_combine_kernel<<<g2, 256, 0, stream>>>(pout, mlbuf, out);
}